// Round 5
// baseline (741.805 us; speedup 1.0000x reference)
//
#include <hip/hip_runtime.h>

// TrigoLinear: out[b,o] = sum_i w_out[o,i]*sin(x[b,i]*w_sin[o,i]+b_sin[o,i]) + b_out[o]
// B=2048, I=256, O=512. 268M v_sin -> trans-pipe bound.
// Floor: 4096 wave-sins/SIMD * 8cy = 32.8K cy ~= 13.7us.
//
// R5 vs R4 (78us, VALUBusy 40%): the R4 killer was s_load weight streams --
// SMEM returns are out-of-order so the compiler drains lgkmcnt(0) before every
// use, flushing prefetches too (no cross-chunk overlap). Fix: weights live in
// LDS, staged ONCE per block; hot loop reads them via broadcast ds_read_b128
// (same addr all lanes: conflict-free, fine-grained partial lgkmcnt waits).
// x stays per-lane in VGPRs, 16-i chunks pipelined on vmcnt. Zero SMEM and
// zero barriers in the loop; vmcnt(x) / lgkmcnt(weights) fully decoupled.
// Single kernel, no prep, no workspace.

#define B_SZ 2048
#define I_SZ 256
#define O_SZ 512

static constexpr float kInv2Pi = 0.15915494309189535f;

__global__ __launch_bounds__(256, 6) void TrigoLinear_kernel(
    const float* __restrict__ x, const float* __restrict__ w,
    const float* __restrict__ bias, float* __restrict__ out) {
  // Block = 256 threads = 256 consecutive b's; one o-pair per block.
  // WPK[i2][0] = {a_e0, a_o0, c_e0, c_o0}  (o0; a=w_sin/2pi, c=b_sin/2pi)
  // WPK[i2][1] = {a_e1, a_o1, c_e1, c_o1}  (o1)
  // WPK[i2][2] = {w_e0, w_o0, w_e1, w_o1}  (w_out)
  __shared__ float4 WPK[128][3];  // 6 KB

  const int tid = threadIdx.x;
  const int btile = blockIdx.x & 7;  // 8 b-tiles of 256
  const int og = blockIdx.x >> 3;    // 256 o-pairs
  const int o0 = og * 2, o1 = o0 + 1;
  const int b = btile * 256 + tid;

  // ---- stage packed weights once (threads 0..127; ~6KB, coalesced) ----
  if (tid < 128) {
    const int i2 = tid;
    const float4 wq0 =
        *reinterpret_cast<const float4*>(&w[(size_t)o0 * 2 * I_SZ + 4 * i2]);
    const float4 wq1 =
        *reinterpret_cast<const float4*>(&w[(size_t)o1 * 2 * I_SZ + 4 * i2]);
    // bias rows have odd stride 257 -> only 4B-aligned: scalar loads
    const float be0 = bias[(size_t)o0 * (I_SZ + 1) + 2 * i2];
    const float bo0 = bias[(size_t)o0 * (I_SZ + 1) + 2 * i2 + 1];
    const float be1 = bias[(size_t)o1 * (I_SZ + 1) + 2 * i2];
    const float bo1 = bias[(size_t)o1 * (I_SZ + 1) + 2 * i2 + 1];
    WPK[i2][0] = make_float4(wq0.y * kInv2Pi, wq0.w * kInv2Pi,
                             be0 * kInv2Pi, bo0 * kInv2Pi);
    WPK[i2][1] = make_float4(wq1.y * kInv2Pi, wq1.w * kInv2Pi,
                             be1 * kInv2Pi, bo1 * kInv2Pi);
    WPK[i2][2] = make_float4(wq0.x, wq0.z, wq1.x, wq1.z);
  }

  const float4* __restrict__ xrow =
      reinterpret_cast<const float4*>(x + (size_t)b * I_SZ);

  float acc0 = 0.f, acc1 = 0.f;

  // first x chunk (16 i = 4 float4) in flight before the barrier
  float4 xq[4], xn[4];
#pragma unroll
  for (int k = 0; k < 4; ++k) xq[k] = xrow[k];

  __syncthreads();  // the only barrier

#pragma unroll 1
  for (int c = 0; c < 16; ++c) {  // 16 chunks x 16 i
    if (c < 15) {
#pragma unroll
      for (int k = 0; k < 4; ++k) xn[k] = xrow[(c + 1) * 4 + k];  // prefetch
    }
#pragma unroll
    for (int q = 0; q < 8; ++q) {  // i-pair within chunk
      const int i2 = c * 8 + q;
      const float4 xv = xq[q >> 1];
      const float xe = (q & 1) ? xv.z : xv.x;  // i = 16c + 2q
      const float xo = (q & 1) ? xv.w : xv.y;  // i = 16c + 2q + 1
      const float4 A0 = WPK[i2][0];  // broadcast ds_read_b128
      const float4 A1 = WPK[i2][1];
      const float4 WW = WPK[i2][2];
      acc0 = __builtin_fmaf(
          __builtin_amdgcn_sinf(__builtin_fmaf(xe, A0.x, A0.z)), WW.x, acc0);
      acc0 = __builtin_fmaf(
          __builtin_amdgcn_sinf(__builtin_fmaf(xo, A0.y, A0.w)), WW.y, acc0);
      acc1 = __builtin_fmaf(
          __builtin_amdgcn_sinf(__builtin_fmaf(xe, A1.x, A1.z)), WW.z, acc1);
      acc1 = __builtin_fmaf(
          __builtin_amdgcn_sinf(__builtin_fmaf(xo, A1.y, A1.w)), WW.w, acc1);
    }
    if (c < 15) {
#pragma unroll
      for (int k = 0; k < 4; ++k) xq[k] = xn[k];
    }
  }

  out[(size_t)b * O_SZ + o0] = acc0 + bias[(size_t)o0 * (I_SZ + 1) + I_SZ];
  out[(size_t)b * O_SZ + o1] = acc1 + bias[(size_t)o1 * (I_SZ + 1) + I_SZ];
}

extern "C" void kernel_launch(void* const* d_in, const int* in_sizes, int n_in,
                              void* d_out, int out_size, void* d_ws, size_t ws_size,
                              hipStream_t stream) {
  const float* x = (const float*)d_in[0];     // (2048, 256) f32
  const float* w = (const float*)d_in[1];     // (512, 256, 2) f32
  const float* bias = (const float*)d_in[2];  // (512, 257) f32
  float* out = (float*)d_out;                 // (2048, 512) f32

  const int grid = (B_SZ / 256) * (O_SZ / 2);  // 8 * 256 = 2048 blocks
  TrigoLinear_kernel<<<dim3(grid), dim3(256), 0, stream>>>(x, w, bias, out);
}

// Round 6
// 169.283 us; speedup vs baseline: 4.3820x; 4.3820x over previous
//
#include <hip/hip_runtime.h>

// TrigoLinear: out[b,o] = sum_i w_out[o,i]*sin(x[b,i]*w_sin[o,i]+b_sin[o,i]) + b_out[o]
// B=2048, I=256, O=512. 268M v_sin -> trans-pipe bound.
// Floor: 4096 wave-sins/SIMD * 8cy = 32.8K cy ~= 13.7us.
//
// R6 pipe ledger (lessons R2/R4/R5):
//  - LDS pipe: broadcast ds_read costs like full reads (reg-write limited);
//    any per-sin LDS delivery oversubscribes 4 SIMDs sharing one pipe. R2=51us
//    was LDS-bound. => ZERO LDS.
//  - SMEM: compiler emits just-in-time s_load + lgkmcnt(0) drains (R4=40%
//    busy). => ZERO SMEM in the loop (opaque VGPR-0 in the weight index stops
//    uniform-load scalarization).
//  - Scratch: R5's register arrays spilled (FETCH 1.1GB). => named regs only.
//  - Everything rides vmcnt: x per-lane dwordx4; weights broadcast dwordx4
//    (same addr all lanes = 1 line) from prep-packed SoA planes, one 4-i chunk
//    double-buffered ahead. Issue cost per sin = pk_fma + sin + pk_fma/2
//    ~= 4cy per 8cy trans -> 6 waves/SIMD saturate the trans pipe.

#define B_SZ 2048
#define I_SZ 256
#define O_SZ 512

typedef float f32x2 __attribute__((ext_vector_type(2)));
static constexpr float kInv2Pi = 0.15915494309189535f;

static __device__ __forceinline__ f32x2 mk2(float a, float b) {
  f32x2 r; r.x = a; r.y = b; return r;
}
#if __has_builtin(__builtin_elementwise_fma)
static __device__ __forceinline__ f32x2 fma2(f32x2 a, f32x2 b, f32x2 c) {
  return __builtin_elementwise_fma(a, b, c);  // v_pk_fma_f32
}
#else
static __device__ __forceinline__ f32x2 fma2(f32x2 a, f32x2 b, f32x2 c) {
  return mk2(__builtin_fmaf(a.x, b.x, c.x), __builtin_fmaf(a.y, b.y, c.y));
}
#endif
static __device__ __forceinline__ f32x2 sin2(f32x2 v) {
  return mk2(__builtin_amdgcn_sinf(v.x), __builtin_amdgcn_sinf(v.y));
}

// SoA planes in ws: A[o][i]=w_sin/2pi, C[o][i]=b_sin/2pi, W[o][i]=w_out
__global__ __launch_bounds__(256) void prep_kernel(
    const float* __restrict__ w, const float* __restrict__ bias,
    float* __restrict__ A, float* __restrict__ C, float* __restrict__ W) {
  const int o = blockIdx.x;    // 512
  const int i = threadIdx.x;   // 256
  const float2 wp = *reinterpret_cast<const float2*>(&w[(size_t)o * 2 * I_SZ + 2 * i]);
  A[o * I_SZ + i] = wp.y * kInv2Pi;
  C[o * I_SZ + i] = bias[o * (I_SZ + 1) + i] * kInv2Pi;
  W[o * I_SZ + i] = wp.x;
}

__global__ __launch_bounds__(256, 6) void TrigoLinear_kernel(
    const float* __restrict__ x, const float* __restrict__ A,
    const float* __restrict__ C, const float* __restrict__ W,
    const float* __restrict__ bias, float* __restrict__ out) {
  const int tid = threadIdx.x;
  const int lane = tid & 63;
  const int wave = tid >> 6;
  const int btile = blockIdx.x & 31;  // 32 b-tiles of 64
  const int og = blockIdx.x >> 5;     // 64 o-groups of 8
  const int o0 = og * 8 + wave * 2;   // this wave's o-pair
  const int b = btile * 64 + lane;

  // opaque zero: keeps the weight index formally divergent so the compiler
  // emits global_load (vmcnt, pipelined) instead of s_load (lgkm JIT drains).
  int opq0;
  asm("v_mov_b32 %0, 0" : "=v"(opq0));
  const int wi = o0 * I_SZ + opq0;  // float index into A/C/W planes
  const int xi = b * I_SZ;

  f32x2 acc0a = mk2(0.f, 0.f), acc0b = mk2(0.f, 0.f);
  f32x2 acc1a = mk2(0.f, 0.f), acc1b = mk2(0.f, 0.f);

  // two named register sets (P/Q), one 4-i chunk each — NO arrays (rule #20)
  float4 Px, Pa0, Pc0, Pw0, Pa1, Pc1, Pw1;
  float4 Qx, Qa0, Qc0, Qw0, Qa1, Qc1, Qw1;

#define LD4(base, off) (*reinterpret_cast<const float4*>((base) + (off)))
#define STAGE(S, cc)                                            \
  do {                                                          \
    const int _o = (cc) << 2;                                   \
    S##x  = LD4(x, xi + _o);                                    \
    S##a0 = LD4(A, wi + _o);                                    \
    S##c0 = LD4(C, wi + _o);                                    \
    S##w0 = LD4(W, wi + _o);                                    \
    S##a1 = LD4(A, wi + I_SZ + _o);                             \
    S##c1 = LD4(C, wi + I_SZ + _o);                             \
    S##w1 = LD4(W, wi + I_SZ + _o);                             \
  } while (0)

#define COMP(S)                                                               \
  do {                                                                        \
    const f32x2 xlo = mk2(S##x.x, S##x.y);                                    \
    const f32x2 xhi = mk2(S##x.z, S##x.w);                                    \
    acc0a = fma2(sin2(fma2(xlo, mk2(S##a0.x, S##a0.y), mk2(S##c0.x, S##c0.y))), \
                 mk2(S##w0.x, S##w0.y), acc0a);                               \
    acc0b = fma2(sin2(fma2(xhi, mk2(S##a0.z, S##a0.w), mk2(S##c0.z, S##c0.w))), \
                 mk2(S##w0.z, S##w0.w), acc0b);                               \
    acc1a = fma2(sin2(fma2(xlo, mk2(S##a1.x, S##a1.y), mk2(S##c1.x, S##c1.y))), \
                 mk2(S##w1.x, S##w1.y), acc1a);                               \
    acc1b = fma2(sin2(fma2(xhi, mk2(S##a1.z, S##a1.w), mk2(S##c1.z, S##c1.w))), \
                 mk2(S##w1.z, S##w1.w), acc1b);                               \
  } while (0)

  STAGE(P, 0);
#pragma unroll 1
  for (int c = 0; c < 64; c += 2) {  // 64 chunks of 4 i
    STAGE(Q, c + 1);
    COMP(P);
    STAGE(P, (c + 2) & 63);  // wraps to chunk 0 on last iter (harmless)
    COMP(Q);
  }
#undef LD4
#undef STAGE
#undef COMP

  const float out0 =
      acc0a.x + acc0a.y + acc0b.x + acc0b.y + bias[(size_t)o0 * (I_SZ + 1) + I_SZ];
  const float out1 = acc1a.x + acc1a.y + acc1b.x + acc1b.y +
                     bias[(size_t)(o0 + 1) * (I_SZ + 1) + I_SZ];
  out[(size_t)b * O_SZ + o0] = out0;
  out[(size_t)b * O_SZ + o0 + 1] = out1;
}

// correctness-only fallback if ws is too small (never triggered in R2/R4)
__global__ __launch_bounds__(256) void trig_fallback(
    const float* __restrict__ x, const float* __restrict__ w,
    const float* __restrict__ bias, float* __restrict__ out) {
  const int idx = blockIdx.x * 256 + threadIdx.x;  // b*512 + o
  const int b = idx >> 9;
  const int o = idx & 511;
  float acc = bias[o * (I_SZ + 1) + I_SZ];
  for (int i = 0; i < I_SZ; ++i) {
    const float ws = w[(size_t)o * 2 * I_SZ + 2 * i + 1];
    const float wo = w[(size_t)o * 2 * I_SZ + 2 * i];
    const float bs = bias[o * (I_SZ + 1) + i];
    const float rev = __builtin_fmaf(x[(size_t)b * I_SZ + i], ws, bs) * kInv2Pi;
    acc = __builtin_fmaf(__builtin_amdgcn_sinf(rev), wo, acc);
  }
  out[idx] = acc;
}

extern "C" void kernel_launch(void* const* d_in, const int* in_sizes, int n_in,
                              void* d_out, int out_size, void* d_ws, size_t ws_size,
                              hipStream_t stream) {
  const float* x = (const float*)d_in[0];     // (2048, 256) f32
  const float* w = (const float*)d_in[1];     // (512, 256, 2) f32
  const float* bias = (const float*)d_in[2];  // (512, 257) f32
  float* out = (float*)d_out;                 // (2048, 512) f32

  const size_t plane = (size_t)O_SZ * I_SZ;            // 131072 floats
  const size_t need = 3 * plane * sizeof(float);       // 1.5 MB

  if (ws_size >= need) {
    float* A = (float*)d_ws;
    float* C = A + plane;
    float* W = C + plane;
    prep_kernel<<<dim3(O_SZ), dim3(I_SZ), 0, stream>>>(w, bias, A, C, W);
    const int grid = (B_SZ / 64) * (O_SZ / 8);  // 32 * 64 = 2048
    TrigoLinear_kernel<<<dim3(grid), dim3(256), 0, stream>>>(x, A, C, W, bias, out);
  } else {
    trig_fallback<<<dim3(B_SZ * O_SZ / 256), dim3(256), 0, stream>>>(x, w, bias, out);
  }
}

// Round 8
// 129.006 us; speedup vs baseline: 5.7501x; 1.3122x over previous
//
#include <hip/hip_runtime.h>

// TrigoLinear: out[b,o] = sum_i w_out[o,i]*sin(x[b,i]*w_sin[o,i]+b_sin[o,i]) + b_out[o]
// B=2048, I=256, O=512. 268M v_sin -> trans-pipe bound.
// Floor: 4096 wave-sins/SIMD * 8cy = 32.8K cy ~= 13.7us.
//
// R8 design, from the pipe ledger of R2-R7:
//  - LDS per-sin delivery dead (broadcast b128 ~12cy reg-writeback; 4 SIMDs
//    share 1 LDS pipe). SMEM streams dead (OoO returns -> lgkmcnt(0) drains).
//    Hand-counted vmcnt asm pipelines produced garbage twice (R3/R7). So:
//    plain C++ loads only (compiler-owned waitcnts = correctness guaranteed),
//    all traffic on vmcnt.
//  - o-oct per wave: x L2 traffic = 2MB*(512/8)/L1-sharing ~ 32MB (o-mult=2
//    was ~0.5GB = L2-saturated, R2's hidden stall). Issue/16 sins ~90cy vs
//    128cy trans -> 30% slack; 2 waves/SIMD saturate the trans pipe.
//  - Anti-collapse (R6's VGPR=36 failure): __launch_bounds__(256,2) gives the
//    scheduler a 256-VGPR budget (no pressure excuse), 4-deep NAMED rotation
//    buffers P/Q/R/S (prefetch distance ~3 compute stages ~ 390cy > L2 lat),
//    sched_group_barrier VMEM/ALU clustering hints (T19).
//  - Weights prep-packed per (o-oct g, 2i-chunk c): 48 floats = a-pairs,
//    c-pairs (pre-scaled 1/2pi), w-pairs -> 12 dwordx4 + 1 dwordx2(x) per
//    stage; v_pk_fma_f32 via __builtin_elementwise_fma (R6-validated).
//  - opq VGPR-0 mixed into weight address keeps loads on the vector path
//    (stops uniform-load scalarization; R6-validated).

#define B_SZ 2048
#define I_SZ 256
#define O_SZ 512
#define NCHUNK 128            // chunks of 2 i
#define GSTRIDE (NCHUNK * 48) // floats per o-oct group in ws

typedef float f32x2 __attribute__((ext_vector_type(2)));
typedef float f32x4 __attribute__((ext_vector_type(4)));

static constexpr float kInv2Pi = 0.15915494309189535f;

static __device__ __forceinline__ f32x2 mk2(float a, float b) {
  f32x2 r; r.x = a; r.y = b; return r;
}
static __device__ __forceinline__ f32x2 fma2(f32x2 a, f32x2 b, f32x2 c) {
#if __has_builtin(__builtin_elementwise_fma)
  return __builtin_elementwise_fma(a, b, c);  // v_pk_fma_f32
#else
  return mk2(__builtin_fmaf(a.x, b.x, c.x), __builtin_fmaf(a.y, b.y, c.y));
#endif
}
static __device__ __forceinline__ f32x2 sin2(f32x2 v) {
  return mk2(__builtin_amdgcn_sinf(v.x), __builtin_amdgcn_sinf(v.y));
}

// ws[g*GSTRIDE + c*48]: [0:16)=a-pairs (o'=0..7 at 2o'), [16:32)=c-pairs,
// [32:48)=w-pairs. a,c pre-scaled by 1/2pi. (o = 8g + o', i = 2c, 2c+1)
__global__ __launch_bounds__(128) void prep_kernel(const float* __restrict__ w,
                                                   const float* __restrict__ bias,
                                                   float* __restrict__ wsb) {
  const int o = blockIdx.x;   // 512
  const int c = threadIdx.x;  // 128
  const float4 wq = *reinterpret_cast<const float4*>(&w[(size_t)o * 512 + c * 4]);
  const float b0 = bias[(size_t)o * 257 + 2 * c];
  const float b1 = bias[(size_t)o * 257 + 2 * c + 1];
  float* dst = wsb + (size_t)(o >> 3) * GSTRIDE + (size_t)c * 48;
  const int op = (o & 7) * 2;
  dst[op] = wq.y * kInv2Pi;       dst[op + 1] = wq.w * kInv2Pi;
  dst[16 + op] = b0 * kInv2Pi;    dst[16 + op + 1] = b1 * kInv2Pi;
  dst[32 + op] = wq.x;            dst[32 + op + 1] = wq.z;
}

__global__ __launch_bounds__(256, 2) void TrigoLinear_kernel(
    const float* __restrict__ x, const float* __restrict__ wsb,
    const float* __restrict__ bias, float* __restrict__ out) {
  const int tid = threadIdx.x;
  const int lane = tid & 63;
  const int wave = tid >> 6;
  const int btile = blockIdx.x & 31;  // block's 4 waves share btile -> x L1 hits
  const int gq = blockIdx.x >> 5;     // 16 g-quads
  const int g = gq * 4 + wave;        // o-oct 0..63
  const int b = btile * 64 + lane;

  // opaque 0 keeps weight addresses on the vector-memory path (no s_load).
  int opq;
  asm("v_mov_b32 %0, 0" : "=v"(opq));
  const float* __restrict__ wbase = wsb + (size_t)g * GSTRIDE + opq;
  const float* __restrict__ xrow = x + (size_t)b * I_SZ;

  f32x2 acc0 = mk2(0.f, 0.f), acc1 = acc0, acc2 = acc0, acc3 = acc0;
  f32x2 acc4 = acc0, acc5 = acc0, acc6 = acc0, acc7 = acc0;

  // 4-deep rotation buffers, all named (rule #20: no arrays)
  f32x4 Pw0, Pw1, Pw2, Pw3, Pw4, Pw5, Pw6, Pw7, Pw8, Pw9, Pw10, Pw11; f32x2 Pxv;
  f32x4 Qw0, Qw1, Qw2, Qw3, Qw4, Qw5, Qw6, Qw7, Qw8, Qw9, Qw10, Qw11; f32x2 Qxv;
  f32x4 Rw0, Rw1, Rw2, Rw3, Rw4, Rw5, Rw6, Rw7, Rw8, Rw9, Rw10, Rw11; f32x2 Rxv;
  f32x4 Sw0, Sw1, Sw2, Sw3, Sw4, Sw5, Sw6, Sw7, Sw8, Sw9, Sw10, Sw11; f32x2 Sxv;

#define LOADS(S, cc)                                           \
  do {                                                         \
    const int _c = (cc) > 127 ? 127 : (cc); /* tail clamp */   \
    const float* _wp = wbase + _c * 48;                        \
    S##w0 = *(const f32x4*)(_wp + 0);                          \
    S##w1 = *(const f32x4*)(_wp + 4);                          \
    S##w2 = *(const f32x4*)(_wp + 8);                          \
    S##w3 = *(const f32x4*)(_wp + 12);                         \
    S##w4 = *(const f32x4*)(_wp + 16);                         \
    S##w5 = *(const f32x4*)(_wp + 20);                         \
    S##w6 = *(const f32x4*)(_wp + 24);                         \
    S##w7 = *(const f32x4*)(_wp + 28);                         \
    S##w8 = *(const f32x4*)(_wp + 32);                         \
    S##w9 = *(const f32x4*)(_wp + 36);                         \
    S##w10 = *(const f32x4*)(_wp + 40);                        \
    S##w11 = *(const f32x4*)(_wp + 44);                        \
    S##xv = *(const f32x2*)(xrow + _c * 2);                    \
  } while (0)

#define PAIR(V, hi) ((hi) ? mk2((V).z, (V).w) : mk2((V).x, (V).y))
#define CO(S, A, C, W, hi, acc) \
  acc = fma2(sin2(fma2(S##xv, PAIR(A, hi), PAIR(C, hi))), PAIR(W, hi), acc)
#define COMP(S)                             \
  do {                                      \
    CO(S, S##w0, S##w4, S##w8, 0, acc0);    \
    CO(S, S##w0, S##w4, S##w8, 1, acc1);    \
    CO(S, S##w1, S##w5, S##w9, 0, acc2);    \
    CO(S, S##w1, S##w5, S##w9, 1, acc3);    \
    CO(S, S##w2, S##w6, S##w10, 0, acc4);   \
    CO(S, S##w2, S##w6, S##w10, 1, acc5);   \
    CO(S, S##w3, S##w7, S##w11, 0, acc6);   \
    CO(S, S##w3, S##w7, S##w11, 1, acc7);   \
  } while (0)

// T19: describe the body interleave [13 VMEM_READ][~40 ALU] x4
#define SGB_BODY()                                            \
  do {                                                        \
    __builtin_amdgcn_sched_group_barrier(0x20, 13, 0);        \
    __builtin_amdgcn_sched_group_barrier(0x1, 40, 0);         \
    __builtin_amdgcn_sched_group_barrier(0x20, 13, 0);        \
    __builtin_amdgcn_sched_group_barrier(0x1, 40, 0);         \
    __builtin_amdgcn_sched_group_barrier(0x20, 13, 0);        \
    __builtin_amdgcn_sched_group_barrier(0x1, 40, 0);         \
    __builtin_amdgcn_sched_group_barrier(0x20, 13, 0);        \
    __builtin_amdgcn_sched_group_barrier(0x1, 40, 0);         \
  } while (0)

  LOADS(P, 0);
  LOADS(Q, 1);
  LOADS(R, 2);

#pragma unroll 1
  for (int k = 0; k < 32; ++k) {  // 128 chunks of 2 i, 4 per iteration
    const int c4 = k * 4;
    LOADS(S, c4 + 3);
    COMP(P);
    LOADS(P, c4 + 4);
    COMP(Q);
    LOADS(Q, c4 + 5);
    COMP(R);
    LOADS(R, c4 + 6);
    COMP(S);
    SGB_BODY();
  }
#undef LOADS
#undef PAIR
#undef CO
#undef COMP
#undef SGB_BODY

  const int o0 = g * 8;
  f32x4 r0, r1;
  r0.x = acc0.x + acc0.y + bias[(size_t)(o0 + 0) * 257 + 256];
  r0.y = acc1.x + acc1.y + bias[(size_t)(o0 + 1) * 257 + 256];
  r0.z = acc2.x + acc2.y + bias[(size_t)(o0 + 2) * 257 + 256];
  r0.w = acc3.x + acc3.y + bias[(size_t)(o0 + 3) * 257 + 256];
  r1.x = acc4.x + acc4.y + bias[(size_t)(o0 + 4) * 257 + 256];
  r1.y = acc5.x + acc5.y + bias[(size_t)(o0 + 5) * 257 + 256];
  r1.z = acc6.x + acc6.y + bias[(size_t)(o0 + 6) * 257 + 256];
  r1.w = acc7.x + acc7.y + bias[(size_t)(o0 + 7) * 257 + 256];
  *reinterpret_cast<f32x4*>(out + (size_t)b * O_SZ + o0) = r0;
  *reinterpret_cast<f32x4*>(out + (size_t)b * O_SZ + o0 + 4) = r1;
}

// correctness-only fallback if ws is too small
__global__ __launch_bounds__(256) void trig_fallback(
    const float* __restrict__ x, const float* __restrict__ w,
    const float* __restrict__ bias, float* __restrict__ out) {
  const int idx = blockIdx.x * 256 + threadIdx.x;  // b*512 + o
  const int b = idx >> 9;
  const int o = idx & 511;
  float acc = bias[o * (I_SZ + 1) + I_SZ];
  for (int i = 0; i < I_SZ; ++i) {
    const float ws = w[(size_t)o * 2 * I_SZ + 2 * i + 1];
    const float wo = w[(size_t)o * 2 * I_SZ + 2 * i];
    const float bs = bias[o * (I_SZ + 1) + i];
    const float rev = __builtin_fmaf(x[(size_t)b * I_SZ + i], ws, bs) * kInv2Pi;
    acc = __builtin_fmaf(__builtin_amdgcn_sinf(rev), wo, acc);
  }
  out[idx] = acc;
}

extern "C" void kernel_launch(void* const* d_in, const int* in_sizes, int n_in,
                              void* d_out, int out_size, void* d_ws, size_t ws_size,
                              hipStream_t stream) {
  const float* x = (const float*)d_in[0];     // (2048, 256) f32
  const float* w = (const float*)d_in[1];     // (512, 256, 2) f32
  const float* bias = (const float*)d_in[2];  // (512, 257) f32
  float* out = (float*)d_out;                 // (2048, 512) f32

  const size_t need = (size_t)64 * GSTRIDE * sizeof(float);  // 1.5 MB

  if (ws_size >= need) {
    float* wsb = (float*)d_ws;
    prep_kernel<<<dim3(O_SZ), dim3(NCHUNK), 0, stream>>>(w, bias, wsb);
    // 32 btiles x 16 g-quads = 512 blocks (2/CU, 8 waves/CU, 2/SIMD)
    TrigoLinear_kernel<<<dim3(512), dim3(256), 0, stream>>>(x, wsb, bias, out);
  } else {
    trig_fallback<<<dim3(B_SZ * O_SZ / 256), dim3(256), 0, stream>>>(x, w, bias, out);
  }
}